// Round 9
// baseline (198.772 us; speedup 1.0000x reference)
//
#include <hip/hip_runtime.h>

#define E 4096
#define H 32
#define L 8192
#define SCALE 0.08838834764831845f  // 1/sqrt(128)

typedef float fv4 __attribute__((ext_vector_type(4)));

__device__ __forceinline__ fv4 ntload4(const float* p) {
  return __builtin_nontemporal_load(reinterpret_cast<const fv4*>(p));
}
__device__ __forceinline__ void ntstore4(float* p, fv4 v) {
  __builtin_nontemporal_store(v, reinterpret_cast<fv4*>(p));
}

// workspace layout (float offsets) — total 382016 floats = 1.53 MB
#define WS_QACC  0            // 4 reps x 4096
#define WS_KACC  16384        // 4 reps x 4096
#define WS_VACC  32768        // 4 reps x 4096
#define WS_NUMP  49152        // 16 reps x 4096
#define WS_DENP  114688       // 16 reps x 64
#define WS_ZERO  115712       // zero everything above
#define WS_NUM   115712       // 4096
#define WS_DEN   119808       // 64
#define WS_OPART 119872       // 64 x 4096

// ---------------- K0: zero accumulators ------------------------------------
__global__ __launch_bounds__(256) void zero_ws(float* __restrict__ ws) {
  int i = blockIdx.x * 256 + threadIdx.x;
  if (i < WS_ZERO) ws[i] = 0.f;
}

// ---------------- K1: q GEMV only (the sole prerequisite for streaming) -----
__global__ __launch_bounds__(256) void gemv_q(const float* __restrict__ x,
    const float* __restrict__ Wq, float* __restrict__ qacc) {
  int b = blockIdx.x;            // 256 blocks: 64 chunks x 4 col-groups
  int chunk = b >> 2, g = b & 3, t = threadIdx.x;
  float* acc = qacc + ((chunk & 3) << 12);   // 4-rep replication
  int j = (g << 10) + (t << 2);
  float ax = 0.f, ay = 0.f, az = 0.f, aw = 0.f;
  int i0 = chunk << 6;
  #pragma unroll 8
  for (int r = 0; r < 64; ++r) {
    int i = i0 + r;
    float xi = x[i];
    const fv4 w4 = ntload4(Wq + (size_t)i * E + j);
    ax += xi * w4.x; ay += xi * w4.y; az += xi * w4.z; aw += xi * w4.w;
  }
  atomicAdd(acc + j + 0, ax);
  atomicAdd(acc + j + 1, ay);
  atomicAdd(acc + j + 2, az);
  atomicAdd(acc + j + 3, aw);
}

// ---------------- K2: MEGA = kv streaming (512 blocks) + Wk/Wv GEMV (256) ---
#define NSLOTS 16

__device__ __forceinline__ void ld(int o, int t,
    const float* __restrict__ kin, const float* __restrict__ vin,
    fv4 k4[4], fv4 v4[4]) {
  const float* ks = kin + (size_t)(o + 1) * E;
  const float* vs = vin + (size_t)(o + 1) * E;
  #pragma unroll
  for (int c = 0; c < 4; ++c) {
    int e = (c << 10) + (t << 2);
    k4[c] = ntload4(ks + e);
    v4[c] = ntload4(vs + e);
  }
}

__device__ __forceinline__ void proc(int o, int s, int t,
    const fv4 k4[4], const fv4 v4[4], const fv4 q4[4],
    float* __restrict__ kout, float* __restrict__ vout,
    float accx[4], float accy[4], float accz[4], float accw[4],
    float* wlds, int* flags) {
  float* kd = kout + (size_t)o * E;
  float* vd = vout + (size_t)o * E;
  #pragma unroll
  for (int c = 0; c < 4; ++c) {
    int e = (c << 10) + (t << 2);
    ntstore4(kd + e, k4[c]);
    ntstore4(vd + e, v4[c]);
  }
  bool nz = false;
  #pragma unroll
  for (int c = 0; c < 4; ++c) {
    float pp = k4[c].x * q4[c].x + k4[c].y * q4[c].y +
               k4[c].z * q4[c].z + k4[c].w * q4[c].w;
    #pragma unroll
    for (int off = 16; off >= 1; off >>= 1)
      pp += __shfl_xor(pp, off);   // head h = c*8 + (t>>5), dot over 32 lanes
    float w = __expf(pp * SCALE);
    accx[c] += w * v4[c].x; accy[c] += w * v4[c].y;
    accz[c] += w * v4[c].z; accw[c] += w * v4[c].w;
    if ((t & 31) == 0) wlds[(s << 5) + (c << 3) + (t >> 5)] = w;
    nz = nz || v4[c].x != 0.f || v4[c].y != 0.f || v4[c].z != 0.f || v4[c].w != 0.f;
  }
  unsigned long long b = __ballot(nz);
  if ((t & 63) == 0 && b != 0ULL) atomicOr(&flags[s], 1);
}

__global__ __launch_bounds__(256, 3) void mega(
    const float* __restrict__ kin, const float* __restrict__ vin,
    const float* __restrict__ x,
    const float* __restrict__ Wk, const float* __restrict__ Wv,
    const float* __restrict__ bq, const float* __restrict__ qacc,
    float* __restrict__ kacc, float* __restrict__ vacc,
    float* __restrict__ kout, float* __restrict__ vout,
    float* __restrict__ nump, float* __restrict__ denp) {
  int bid = blockIdx.x;
  int t = threadIdx.x;
  if (bid >= 512) {
    // ---- Wk/Wv GEMV blocks (overlap with streaming) ----
    int b = bid - 512;             // 256: 2 mats x 32 chunks x 4 col-groups
    int mat = b >> 7, rem = b & 127;
    int chunk = rem >> 2, g = rem & 3;
    const float* W = mat ? Wv : Wk;
    float* acc = (mat ? vacc : kacc) + ((chunk & 3) << 12);
    int j = (g << 10) + (t << 2);
    float ax = 0.f, ay = 0.f, az = 0.f, aw = 0.f;
    int i0 = chunk << 7;
    #pragma unroll 8
    for (int r = 0; r < 128; ++r) {
      int i = i0 + r;
      float xi = x[i];
      const fv4 w4 = ntload4(W + (size_t)i * E + j);
      ax += xi * w4.x; ay += xi * w4.y; az += xi * w4.z; aw += xi * w4.w;
    }
    atomicAdd(acc + j + 0, ax);
    atomicAdd(acc + j + 1, ay);
    atomicAdd(acc + j + 2, az);
    atomicAdd(acc + j + 3, aw);
    return;
  }
  // ---- streaming blocks: slots [base, base+16) ∩ [0, 8191) ----
  __shared__ float wlds[NSLOTS * 32];
  __shared__ int flags[NSLOTS];
  for (int s = t; s < NSLOTS; s += 256) flags[s] = 0;
  fv4 q4[4];
  #pragma unroll
  for (int c = 0; c < 4; ++c) {
    int e = (c << 10) + (t << 2);
    fv4 qa = *reinterpret_cast<const fv4*>(qacc + e);
    #pragma unroll
    for (int r = 1; r < 4; ++r)
      qa += *reinterpret_cast<const fv4*>(qacc + (r << 12) + e);
    q4[c] = qa + *reinterpret_cast<const fv4*>(bq + e);
  }
  __syncthreads();   // flags init visible

  float accx[4] = {0,0,0,0}, accy[4] = {0,0,0,0};
  float accz[4] = {0,0,0,0}, accw[4] = {0,0,0,0};
  int base = bid * NSLOTS;

  fv4 kA[4], vA[4], kB[4], vB[4];
  ld(base, t, kin, vin, kA, vA);
  #pragma unroll
  for (int sp = 0; sp < NSLOTS; sp += 2) {
    int oB = base + sp + 1;
    bool haveB = oB < L - 1;       // slot 8191 handled by finish kernel
    if (haveB) ld(oB, t, kin, vin, kB, vB);
    proc(base + sp, sp, t, kA, vA, q4, kout, vout, accx, accy, accz, accw,
         wlds, flags);             // even slots always < 8191
    if (sp + 2 < NSLOTS) ld(base + sp + 2, t, kin, vin, kA, vA);
    if (haveB) proc(oB, sp + 1, t, kB, vB, q4, kout, vout, accx, accy,
                    accz, accw, wlds, flags);
  }
  float* np = nump + ((size_t)(bid & 15) << 12);
  #pragma unroll
  for (int c = 0; c < 4; ++c) {
    int e = (c << 10) + (t << 2);
    atomicAdd(np + e + 0, accx[c]);
    atomicAdd(np + e + 1, accy[c]);
    atomicAdd(np + e + 2, accz[c]);
    atomicAdd(np + e + 3, accw[c]);
  }
  __syncthreads();   // wlds + flags complete
  if (t < 32) {
    float d = 0.f;
    #pragma unroll
    for (int s = 0; s < NSLOTS; ++s)
      if (flags[s]) d += wlds[(s << 5) + t];
    atomicAdd(denp + (bid & 15) * 64 + t, d);
  }
}

// ---------------- K3: finish slot 8191 (new token) ---------------------------
__global__ __launch_bounds__(256) void finish(
    const float* __restrict__ bq, const float* __restrict__ bk,
    const float* __restrict__ bv,
    const float* __restrict__ qacc, const float* __restrict__ kacc,
    const float* __restrict__ vacc,
    float* __restrict__ kout, float* __restrict__ vout,
    float* __restrict__ nump, float* __restrict__ denp) {
  int t = threadIdx.x;
  __shared__ float wl[32];
  __shared__ int nzf;
  if (t == 0) nzf = 0;
  fv4 q4[4], k4[4], v4[4];
  #pragma unroll
  for (int c = 0; c < 4; ++c) {
    int e = (c << 10) + (t << 2);
    fv4 qa = *reinterpret_cast<const fv4*>(qacc + e);
    fv4 ka = *reinterpret_cast<const fv4*>(kacc + e);
    fv4 va = *reinterpret_cast<const fv4*>(vacc + e);
    #pragma unroll
    for (int r = 1; r < 4; ++r) {
      qa += *reinterpret_cast<const fv4*>(qacc + (r << 12) + e);
      ka += *reinterpret_cast<const fv4*>(kacc + (r << 12) + e);
      va += *reinterpret_cast<const fv4*>(vacc + (r << 12) + e);
    }
    q4[c] = qa + *reinterpret_cast<const fv4*>(bq + e);
    k4[c] = ka + *reinterpret_cast<const fv4*>(bk + e);
    v4[c] = va + *reinterpret_cast<const fv4*>(bv + e);
  }
  __syncthreads();   // nzf init visible
  float* kd = kout + (size_t)(L - 1) * E;
  float* vd = vout + (size_t)(L - 1) * E;
  bool nz = false;
  float wv[4];
  #pragma unroll
  for (int c = 0; c < 4; ++c) {
    int e = (c << 10) + (t << 2);
    *reinterpret_cast<fv4*>(kd + e) = k4[c];
    *reinterpret_cast<fv4*>(vd + e) = v4[c];
    float pp = k4[c].x * q4[c].x + k4[c].y * q4[c].y +
               k4[c].z * q4[c].z + k4[c].w * q4[c].w;
    #pragma unroll
    for (int off = 16; off >= 1; off >>= 1)
      pp += __shfl_xor(pp, off);
    wv[c] = __expf(pp * SCALE);
    if ((t & 31) == 0) wl[(c << 3) + (t >> 5)] = wv[c];
    nz = nz || v4[c].x != 0.f || v4[c].y != 0.f || v4[c].z != 0.f || v4[c].w != 0.f;
  }
  unsigned long long b = __ballot(nz);
  if ((t & 63) == 0 && b != 0ULL) atomicOr(&nzf, 1);
  __syncthreads();
  if (nzf) {
    #pragma unroll
    for (int c = 0; c < 4; ++c) {
      int e = (c << 10) + (t << 2);
      atomicAdd(nump + e + 0, wv[c] * v4[c].x);
      atomicAdd(nump + e + 1, wv[c] * v4[c].y);
      atomicAdd(nump + e + 2, wv[c] * v4[c].z);
      atomicAdd(nump + e + 3, wv[c] * v4[c].w);
    }
    if (t < 32) atomicAdd(denp + t, wl[t]);
  }
}

// ---------------- K4: sum the 16 replicas ------------------------------------
__global__ __launch_bounds__(256) void merge(const float* __restrict__ nump,
    const float* __restrict__ denp, float* __restrict__ num,
    float* __restrict__ den) {
  int b = blockIdx.x;            // 17 blocks: 16 for num, 1 for den
  int t = threadIdx.x;
  if (b < 16) {
    int e = b * 256 + t;
    float s = 0.f;
    #pragma unroll
    for (int p = 0; p < 16; ++p) s += nump[((size_t)p << 12) + e];
    num[e] = s;
  } else {
    __shared__ float dl[8][32];
    int g = t >> 5, h = t & 31;
    float d = 0.f;
    for (int p = g; p < 16; p += 8) d += denp[p * 64 + h];
    dl[g][h] = d;
    __syncthreads();
    if (t < 32) {
      float s = 0.f;
      #pragma unroll
      for (int g2 = 0; g2 < 8; ++g2) s += dl[g2][t];
      den[t] = s;
    }
  }
}

// ---------------- K5: output GEMV (values = num/den; exclusive partials) ----
__global__ __launch_bounds__(256) void gemv_out(const float* __restrict__ Wo,
    const float* __restrict__ bo, const float* __restrict__ num,
    const float* __restrict__ den, float* __restrict__ opart) {
  int b = blockIdx.x;            // 256 blocks: 64 i-chunks x 4 col-groups
  int chunk = b >> 2, g = b & 3, t = threadIdx.x;
  int j = (g << 10) + (t << 2);
  __shared__ float vals[64];
  int i0 = chunk << 6;
  if (t < 64) vals[t] = num[i0 + t] / den[(i0 + t) >> 7];
  __syncthreads();
  float ax = 0.f, ay = 0.f, az = 0.f, aw = 0.f;
  #pragma unroll 4
  for (int r = 0; r < 64; ++r) {
    int i = i0 + r;
    float vi = vals[r];
    const fv4 w4 = ntload4(Wo + (size_t)i * E + j);
    ax += vi * w4.x; ay += vi * w4.y; az += vi * w4.z; aw += vi * w4.w;
  }
  if (chunk == 0) {
    const fv4 b4 = *reinterpret_cast<const fv4*>(bo + j);
    ax += b4.x; ay += b4.y; az += b4.z; aw += b4.w;
  }
  fv4 val = {ax, ay, az, aw};
  *reinterpret_cast<fv4*>(opart + (chunk << 12) + j) = val;
}

// ---------------- K6: final out_i = sum of 64 chunk partials -----------------
__global__ __launch_bounds__(256) void writeout(const float* __restrict__ opart,
                                                float* __restrict__ out) {
  int i = blockIdx.x * 256 + threadIdx.x;
  float s = 0.f;
  #pragma unroll 8
  for (int c = 0; c < 64; ++c) s += opart[(c << 12) + i];
  out[i] = s;
}

extern "C" void kernel_launch(void* const* d_in, const int* in_sizes, int n_in,
                              void* d_out, int out_size, void* d_ws, size_t ws_size,
                              hipStream_t stream) {
  const float* x   = (const float*)d_in[0];
  const float* vin = (const float*)d_in[1];
  const float* kin = (const float*)d_in[2];
  const float* Wv  = (const float*)d_in[3];
  const float* bv  = (const float*)d_in[4];
  const float* Wq  = (const float*)d_in[5];
  const float* bq  = (const float*)d_in[6];
  const float* Wk  = (const float*)d_in[7];
  const float* bk  = (const float*)d_in[8];
  const float* Wo  = (const float*)d_in[9];
  const float* bo  = (const float*)d_in[10];
  float* out  = (float*)d_out;
  float* vout = out + E;
  float* kout = vout + (size_t)L * E;
  float* ws   = (float*)d_ws;

  float* qacc = ws + WS_QACC;
  float* kacc = ws + WS_KACC;
  float* vacc = ws + WS_VACC;
  float* nump = ws + WS_NUMP;
  float* denp = ws + WS_DENP;
  float* num  = ws + WS_NUM;
  float* den  = ws + WS_DEN;
  float* opart = ws + WS_OPART;

  zero_ws<<<(WS_ZERO + 255) / 256, 256, 0, stream>>>(ws);
  gemv_q<<<256, 256, 0, stream>>>(x, Wq, qacc);
  mega<<<768, 256, 0, stream>>>(kin, vin, x, Wk, Wv, bq, qacc, kacc, vacc,
                                kout, vout, nump, denp);
  finish<<<1, 256, 0, stream>>>(bq, bk, bv, qacc, kacc, vacc,
                                kout, vout, nump, denp);
  merge<<<17, 256, 0, stream>>>(nump, denp, num, den);
  gemv_out<<<256, 256, 0, stream>>>(Wo, bo, num, den, opart);
  writeout<<<16, 256, 0, stream>>>(opart, out);
}